// Round 1
// baseline (404.296 us; speedup 1.0000x reference)
//
#include <hip/hip_runtime.h>
#include <math.h>

#define N_TOK 16384
#define D_DIM 512
#define PI_F 3.14159265358979323846f

// ---------------------------------------------------------------------------
// Kernel 1: per-token complex wave state -> filtered -> L2-normalized -> real
// One block (256 threads) per token; each thread handles 2 of 512 elements.
// x_d = Re(z_d * e^{i*THETA}) / (||z|| + 1e-8),  z_d = (w1*wf1*mod1 + w2*wf2*mod2)*filt_d
// ---------------------------------------------------------------------------
__global__ __launch_bounds__(256) void wave_kernel(
    const int* __restrict__ char_idx, const int* __restrict__ pos,
    float* __restrict__ x) {
  const int n = blockIdx.x;
  const int tid = threadIdx.x;

  const float lam = (float)char_idx[n] / 96.0f;
  const float t = (float)pos[n] / 100.0f;
  const float omega = 2.0f * PI_F * 1.5f;          // 2*pi*ALPHA
  const float kwav = 2.0f * PI_F / 1.7f;           // 2*pi/FRACTAL
  const float lam2 = lam * lam;
  const float ph1 = omega * t - kwav * lam + 0.8f * lam2;
  const float ph2 = omega * t * 1.5f - kwav * lam * 0.7f + 0.8f * lam2 * 1.3f;
  const float a1 = sinf(omega * t + 1.5f * lam);
  const float a2 = cosf(omega * t * 0.8f + 1.5f * lam * 1.2f);
  float sp1, cp1, sp2, cp2;
  sincosf(ph1, &sp1, &cp1);
  sincosf(ph2, &sp2, &cp2);
  const float w1re = a1 * cp1, w1im = a1 * sp1;    // wf1
  const float w2re = a2 * cp2, w2im = a2 * sp2;    // wf2
  const float aAng = (2.0f * PI_F / 512.0f) * lam;           // mod1 angle/elem
  const float bAng = (4.0f * PI_F / 512.0f) * 1.7f * lam;    // mod2 angle/elem

  float zre[2], zim[2];
  float ss = 0.0f;
#pragma unroll
  for (int q = 0; q < 2; ++q) {
    const int d = tid + q * 256;
    const float fi = (float)d;
    const float w1 = 0.6f + 0.4f * sinf(0.1f * fi);
    const float w2 = 0.4f + 0.6f * cosf(0.15f * fi);
    float s1, c1, s2, c2;
    sincosf(aAng * fi, &s1, &c1);
    sincosf(bAng * fi, &s2, &c2);
    // term = w1*wf1*mod1 + w2*wf2*mod2
    const float tre = w1 * (w1re * c1 - w1im * s1) + w2 * (w2re * c2 - w2im * s2);
    const float tim = w1 * (w1re * s1 + w1im * c1) + w2 * (w2re * s2 + w2im * c2);
    // filt_d = 0.7*e^{i*1.5*atan(ln(kv))} + 0.3*e^{i*0.8*sin(0.1*kv)}, kv = d+1
    const float kv = fi + 1.0f;
    const float ang1 = 1.5f * atanf(logf(kv + 1e-10f));
    const float ang2 = 0.8f * sinf(0.1f * kv);
    float fs1, fc1, fs2, fc2;
    sincosf(ang1, &fs1, &fc1);
    sincosf(ang2, &fs2, &fc2);
    const float fre = 0.7f * fc1 + 0.3f * fc2;
    const float fim = 0.7f * fs1 + 0.3f * fs2;
    zre[q] = tre * fre - tim * fim;
    zim[q] = tre * fim + tim * fre;
    ss += zre[q] * zre[q] + zim[q] * zim[q];
  }

  // block reduction of ss (4 waves of 64)
  __shared__ float sbuf[4];
#pragma unroll
  for (int off = 32; off > 0; off >>= 1) ss += __shfl_down(ss, off, 64);
  const int lane = tid & 63, wv = tid >> 6;
  if (lane == 0) sbuf[wv] = ss;
  __syncthreads();
  const float tot = sbuf[0] + sbuf[1] + sbuf[2] + sbuf[3];
  const float inv = 1.0f / (sqrtf(tot) + 1e-8f);
  const float ct = cosf(0.1f), st = sinf(0.1f);    // THETA = 0.1
#pragma unroll
  for (int q = 0; q < 2; ++q) {
    x[(size_t)n * 512 + tid + q * 256] = (zre[q] * ct - zim[q] * st) * inv;
  }
}

// ---------------------------------------------------------------------------
// Kernel 2: xout[n,j] = b[j] + sum_k x[n,k] * W[j,k]   (x @ W.T + b)
// fp32 LDS-tiled GEMM, 64x64 tile, TK=16, 256 threads, 4x4 micro-tile/thread.
// ---------------------------------------------------------------------------
__global__ __launch_bounds__(256) void gemm_kernel(
    const float* __restrict__ x, const float* __restrict__ W,
    const float* __restrict__ b, float* __restrict__ xout) {
  __shared__ float As[16][65];
  __shared__ float Bs[16][65];
  const int bm = blockIdx.x * 64;   // token tile
  const int bn = blockIdx.y * 64;   // output-dim tile
  const int tid = threadIdx.x;
  const int tx = tid & 15, ty = tid >> 4;
  const int kk = tid & 15, r = tid >> 4;

  float acc[4][4] = {};
  for (int kb = 0; kb < 512; kb += 16) {
#pragma unroll
    for (int q = 0; q < 4; ++q) {
      const int row = r + q * 16;
      As[kk][row] = x[(size_t)(bm + row) * 512 + kb + kk];
      Bs[kk][row] = W[(size_t)(bn + row) * 512 + kb + kk];
    }
    __syncthreads();
#pragma unroll
    for (int k = 0; k < 16; ++k) {
      float a[4], bb[4];
#pragma unroll
      for (int i = 0; i < 4; ++i) a[i] = As[k][ty * 4 + i];
#pragma unroll
      for (int j = 0; j < 4; ++j) bb[j] = Bs[k][tx * 4 + j];
#pragma unroll
      for (int i = 0; i < 4; ++i)
#pragma unroll
        for (int j = 0; j < 4; ++j) acc[i][j] += a[i] * bb[j];
    }
    __syncthreads();
  }
#pragma unroll
  for (int i = 0; i < 4; ++i) {
    const int n = bm + ty * 4 + i;
#pragma unroll
    for (int j = 0; j < 4; ++j) {
      const int jj = bn + tx * 4 + j;
      xout[(size_t)n * 512 + jj] = acc[i][j] + b[jj];
    }
  }
}

// ---------------------------------------------------------------------------
// Kernel 3: LayerNorm + noise + quaternion embedding, fused.
// One block per token. Writes float4 {y,q1,q2,q3} per (n,d) -> coalesced 16B.
// ---------------------------------------------------------------------------
__global__ __launch_bounds__(256) void epilogue_kernel(
    const float* __restrict__ xout, const int* __restrict__ char_idx,
    const float* __restrict__ gamma, const float* __restrict__ beta_ln,
    const float* __restrict__ noise, const float* __restrict__ sem,
    float4* __restrict__ out) {
  const int n = blockIdx.x;
  const int tid = threadIdx.x;
  float v[2];
  v[0] = xout[(size_t)n * 512 + tid];
  v[1] = xout[(size_t)n * 512 + tid + 256];
  float s = v[0] + v[1];
  float s2 = v[0] * v[0] + v[1] * v[1];
  __shared__ float sbuf[8];
#pragma unroll
  for (int off = 32; off > 0; off >>= 1) {
    s += __shfl_down(s, off, 64);
    s2 += __shfl_down(s2, off, 64);
  }
  const int lane = tid & 63, wv = tid >> 6;
  if (lane == 0) { sbuf[wv] = s; sbuf[4 + wv] = s2; }
  __syncthreads();
  const float sum = sbuf[0] + sbuf[1] + sbuf[2] + sbuf[3];
  const float sumsq = sbuf[4] + sbuf[5] + sbuf[6] + sbuf[7];
  const float mu = sum * (1.0f / 512.0f);
  const float var = sumsq * (1.0f / 512.0f) - mu * mu;
  const float rstd = rsqrtf(var + 1e-5f);

  const int c = char_idx[n];
  const float sw0 = sem[c * 4 + 0], sw1 = sem[c * 4 + 1], sw2 = sem[c * 4 + 2];
  const float cpm = (float)c * 0.01f;
#pragma unroll
  for (int q = 0; q < 2; ++q) {
    const int d = tid + q * 256;
    const float y = (v[q] - mu) * rstd * gamma[d] + beta_ln[d]
                    + 0.01f * noise[(size_t)n * 512 + d];
    const float ph = (2.0f * PI_F / 512.0f) * (float)d;
    const float q1 = y * sw0 * cosf(ph + cpm);
    const float q2 = y * sw1 * sinf(ph + cpm * 1.3f);
    const float q3 = y * sw2 * cosf(2.0f * ph + cpm * 0.7f);
    out[(size_t)n * 512 + d] = make_float4(y, q1, q2, q3);
  }
}

extern "C" void kernel_launch(void* const* d_in, const int* in_sizes, int n_in,
                              void* d_out, int out_size, void* d_ws, size_t ws_size,
                              hipStream_t stream) {
  const int* char_idx = (const int*)d_in[0];
  const int* pos      = (const int*)d_in[1];
  const float* W      = (const float*)d_in[2];
  const float* b      = (const float*)d_in[3];
  const float* gamma  = (const float*)d_in[4];
  const float* beta_ln= (const float*)d_in[5];
  const float* noise  = (const float*)d_in[6];
  const float* sem    = (const float*)d_in[7];

  float* x    = (float*)d_ws;                       // [N,512] fp32, 32 MiB
  float* xout = x + (size_t)N_TOK * D_DIM;          // [N,512] fp32, 32 MiB

  wave_kernel<<<N_TOK, 256, 0, stream>>>(char_idx, pos, x);
  dim3 g2(N_TOK / 64, D_DIM / 64);
  gemm_kernel<<<g2, 256, 0, stream>>>(x, W, b, xout);
  epilogue_kernel<<<N_TOK, 256, 0, stream>>>(xout, char_idx, gamma, beta_ln,
                                             noise, sem, (float4*)d_out);
}

// Round 2
// 220.906 us; speedup vs baseline: 1.8302x; 1.8302x over previous
//
#include <hip/hip_runtime.h>
#include <math.h>

#define N_TOK 16384
#define D_DIM 512
#define PI_F 3.14159265358979323846f

typedef __bf16 bf16x8 __attribute__((ext_vector_type(8)));
typedef __bf16 bf16x4 __attribute__((ext_vector_type(4)));
typedef float floatx4 __attribute__((ext_vector_type(4)));

#define GAS __attribute__((address_space(1)))
#define LAS __attribute__((address_space(3)))

// ---------------------------------------------------------------------------
// Kernel A: precompute per-(char, d) tables + convert W to bf16.
//  blocks 0..95   : table[c][d] = {M1re, M1im, M2re, M2im}
//                   M1 = w1(d) * mod1(c,d) * filt(d); M2 = w2(d) * mod2(c,d) * filt(d)
//  blocks 96..351 : W fp32 -> bf16 (float4 -> bf16x4 per thread)
// ---------------------------------------------------------------------------
__global__ __launch_bounds__(256) void setup_kernel(
    const float* __restrict__ W, float4* __restrict__ table,
    __bf16* __restrict__ Wb) {
  const int bid = blockIdx.x;
  const int tid = threadIdx.x;
  if (bid < 96) {
    const float lam = (float)bid / 96.0f;
#pragma unroll
    for (int q = 0; q < 2; ++q) {
      const int d = tid + q * 256;
      const float fi = (float)d;
      float s1, c1, s2, c2;
      sincosf((2.0f * PI_F / 512.0f) * fi * lam, &s1, &c1);          // mod1
      sincosf((4.0f * PI_F / 512.0f) * 1.7f * fi * lam, &s2, &c2);   // mod2
      const float w1 = 0.6f + 0.4f * sinf(0.1f * fi);
      const float w2 = 0.4f + 0.6f * cosf(0.15f * fi);
      const float kv = fi + 1.0f;
      float fs1, fc1, fs2, fc2;
      sincosf(1.5f * atanf(logf(kv + 1e-10f)), &fs1, &fc1);
      sincosf(0.8f * sinf(0.1f * kv), &fs2, &fc2);
      const float fre = 0.7f * fc1 + 0.3f * fc2;
      const float fim = 0.7f * fs1 + 0.3f * fs2;
      table[bid * 512 + d] = make_float4(
          w1 * (c1 * fre - s1 * fim), w1 * (c1 * fim + s1 * fre),
          w2 * (c2 * fre - s2 * fim), w2 * (c2 * fim + s2 * fre));
    }
  } else {
    const int i = (bid - 96) * 256 + tid;   // 65536 float4s = 262144 floats
    const float4 w = ((const float4*)W)[i];
    bf16x4 o;
    o[0] = (__bf16)w.x; o[1] = (__bf16)w.y; o[2] = (__bf16)w.z; o[3] = (__bf16)w.w;
    ((bf16x4*)Wb)[i] = o;
  }
}

// ---------------------------------------------------------------------------
// Kernel B: per-token wave state. z[d] = wf1(n)*M1[c,d] + wf2(n)*M2[c,d];
// x[d] = Re(z * e^{i*0.1}) / (||z|| + 1e-8), written as bf16 for the MFMA GEMM.
// One block per token, 256 threads, 2 elems/thread. No per-element trig.
// ---------------------------------------------------------------------------
__global__ __launch_bounds__(256) void wave_kernel(
    const int* __restrict__ char_idx, const int* __restrict__ pos,
    const float4* __restrict__ table, __bf16* __restrict__ xb) {
  const int n = blockIdx.x;
  const int tid = threadIdx.x;
  const int c = char_idx[n];
  const float lam = (float)c / 96.0f;
  const float t = (float)pos[n] / 100.0f;
  const float omega = 2.0f * PI_F * 1.5f;
  const float kwav = 2.0f * PI_F / 1.7f;
  const float lam2 = lam * lam;
  float sp1, cp1, sp2, cp2;
  sincosf(omega * t - kwav * lam + 0.8f * lam2, &sp1, &cp1);
  sincosf(omega * t * 1.5f - kwav * lam * 0.7f + 1.04f * lam2, &sp2, &cp2);
  const float a1 = sinf(omega * t + 1.5f * lam);
  const float a2 = cosf(omega * t * 0.8f + 1.8f * lam);
  const float w1re = a1 * cp1, w1im = a1 * sp1;
  const float w2re = a2 * cp2, w2im = a2 * sp2;

  float zre[2], zim[2], ss = 0.0f;
#pragma unroll
  for (int q = 0; q < 2; ++q) {
    const int d = tid + q * 256;
    const float4 m = table[c * 512 + d];
    zre[q] = w1re * m.x - w1im * m.y + w2re * m.z - w2im * m.w;
    zim[q] = w1re * m.y + w1im * m.x + w2re * m.w + w2im * m.z;
    ss += zre[q] * zre[q] + zim[q] * zim[q];
  }
  __shared__ float sbuf[4];
#pragma unroll
  for (int off = 32; off > 0; off >>= 1) ss += __shfl_down(ss, off, 64);
  const int lane = tid & 63, wv = tid >> 6;
  if (lane == 0) sbuf[wv] = ss;
  __syncthreads();
  const float inv = 1.0f / (sqrtf(sbuf[0] + sbuf[1] + sbuf[2] + sbuf[3]) + 1e-8f);
  const float ct = cosf(0.1f), st = sinf(0.1f);
#pragma unroll
  for (int q = 0; q < 2; ++q) {
    xb[(size_t)n * 512 + tid + q * 256] = (__bf16)((zre[q] * ct - zim[q] * st) * inv);
  }
}

// ---------------------------------------------------------------------------
// Kernel C: bf16 MFMA GEMM (m97 structure). C[m,n] = sum_k A[m,k]*B[n,k].
// 128x128 tile, BK=32, 256 threads = 4 waves in 2x2, each wave 64x64 via
// 4x4 grid of 16x16x32 MFMA. global_load_lds width=16 staging.
// ---------------------------------------------------------------------------
__global__ __launch_bounds__(256) void mfma_gemm(
    const __bf16* __restrict__ A, const __bf16* __restrict__ B,
    float* __restrict__ C) {
  __shared__ __align__(16) __bf16 As[128 * 32];
  __shared__ __align__(16) __bf16 Bs[128 * 32];
  const int tid = threadIdx.x;
  const int bm = blockIdx.x * 128;
  const int bn = blockIdx.y * 128;
  const int lane = tid & 63, w = tid >> 6;
  const int wm = (w >> 1) * 64, wn = (w & 1) * 64;
  const int lm = lane & 15;             // m/n within 16-tile
  const int lk = (lane >> 4) * 8;       // k offset within 32
  const int srow = tid >> 2;            // staging row 0..63
  const int skc = (tid & 3) * 8;        // staging k-offset

  floatx4 acc[4][4] = {};

  for (int kb = 0; kb < 512; kb += 32) {
    // stage A/B tiles: 128x32 bf16 each = 8KB = 2 wave-sweeps of 16B/lane
    __builtin_amdgcn_global_load_lds(
        (const GAS void*)(A + (size_t)(bm + srow) * 512 + kb + skc),
        (LAS void*)(As + srow * 32 + skc), 16, 0, 0);
    __builtin_amdgcn_global_load_lds(
        (const GAS void*)(A + (size_t)(bm + 64 + srow) * 512 + kb + skc),
        (LAS void*)(As + (64 + srow) * 32 + skc), 16, 0, 0);
    __builtin_amdgcn_global_load_lds(
        (const GAS void*)(B + (size_t)(bn + srow) * 512 + kb + skc),
        (LAS void*)(Bs + srow * 32 + skc), 16, 0, 0);
    __builtin_amdgcn_global_load_lds(
        (const GAS void*)(B + (size_t)(bn + 64 + srow) * 512 + kb + skc),
        (LAS void*)(Bs + (64 + srow) * 32 + skc), 16, 0, 0);
    __syncthreads();

    bf16x8 af[4], bf[4];
#pragma unroll
    for (int i = 0; i < 4; ++i)
      af[i] = *(const bf16x8*)(As + (wm + i * 16 + lm) * 32 + lk);
#pragma unroll
    for (int j = 0; j < 4; ++j)
      bf[j] = *(const bf16x8*)(Bs + (wn + j * 16 + lm) * 32 + lk);
#pragma unroll
    for (int i = 0; i < 4; ++i)
#pragma unroll
      for (int j = 0; j < 4; ++j)
        acc[i][j] = __builtin_amdgcn_mfma_f32_16x16x32_bf16(af[i], bf[j], acc[i][j], 0, 0, 0);
    __syncthreads();
  }

  // C/D layout: col = lane&15, row = (lane>>4)*4 + reg
  const int r0 = (lane >> 4) * 4;
#pragma unroll
  for (int i = 0; i < 4; ++i) {
    const int row = bm + wm + i * 16 + r0;
#pragma unroll
    for (int j = 0; j < 4; ++j) {
      const int col = bn + wn + j * 16 + lm;
#pragma unroll
      for (int r = 0; r < 4; ++r)
        C[(size_t)(row + r) * 512 + col] = acc[i][j][r];
    }
  }
}

// ---------------------------------------------------------------------------
// Kernel D: bias + LayerNorm + noise + quaternion embedding, fused.
// One block per token; float4 {y,q1,q2,q3} stores = coalesced 16B/lane.
// ---------------------------------------------------------------------------
__global__ __launch_bounds__(256) void epilogue_kernel(
    const float* __restrict__ xout, const int* __restrict__ char_idx,
    const float* __restrict__ b, const float* __restrict__ gamma,
    const float* __restrict__ beta_ln, const float* __restrict__ noise,
    const float* __restrict__ sem, float4* __restrict__ out) {
  const int n = blockIdx.x;
  const int tid = threadIdx.x;
  float v[2];
  v[0] = xout[(size_t)n * 512 + tid] + b[tid];
  v[1] = xout[(size_t)n * 512 + tid + 256] + b[tid + 256];
  float s = v[0] + v[1];
  float s2 = v[0] * v[0] + v[1] * v[1];
  __shared__ float sbuf[8];
#pragma unroll
  for (int off = 32; off > 0; off >>= 1) {
    s += __shfl_down(s, off, 64);
    s2 += __shfl_down(s2, off, 64);
  }
  const int lane = tid & 63, wv = tid >> 6;
  if (lane == 0) { sbuf[wv] = s; sbuf[4 + wv] = s2; }
  __syncthreads();
  const float mu = (sbuf[0] + sbuf[1] + sbuf[2] + sbuf[3]) * (1.0f / 512.0f);
  const float var = (sbuf[4] + sbuf[5] + sbuf[6] + sbuf[7]) * (1.0f / 512.0f) - mu * mu;
  const float rstd = rsqrtf(var + 1e-5f);

  const int c = char_idx[n];
  const float sw0 = sem[c * 4 + 0], sw1 = sem[c * 4 + 1], sw2 = sem[c * 4 + 2];
  const float cpm = (float)c * 0.01f;
#pragma unroll
  for (int q = 0; q < 2; ++q) {
    const int d = tid + q * 256;
    const float y = (v[q] - mu) * rstd * gamma[d] + beta_ln[d]
                    + 0.01f * noise[(size_t)n * 512 + d];
    const float ph = (2.0f * PI_F / 512.0f) * (float)d;
    const float q1 = y * sw0 * __cosf(ph + cpm);
    const float q2 = y * sw1 * __sinf(ph + cpm * 1.3f);
    const float q3 = y * sw2 * __cosf(2.0f * ph + cpm * 0.7f);
    out[(size_t)n * 512 + d] = make_float4(y, q1, q2, q3);
  }
}

extern "C" void kernel_launch(void* const* d_in, const int* in_sizes, int n_in,
                              void* d_out, int out_size, void* d_ws, size_t ws_size,
                              hipStream_t stream) {
  const int* char_idx = (const int*)d_in[0];
  const int* pos      = (const int*)d_in[1];
  const float* W      = (const float*)d_in[2];
  const float* b      = (const float*)d_in[3];
  const float* gamma  = (const float*)d_in[4];
  const float* beta_ln= (const float*)d_in[5];
  const float* noise  = (const float*)d_in[6];
  const float* sem    = (const float*)d_in[7];

  // workspace layout
  float4* table = (float4*)d_ws;                        // 96*512*16B = 768 KB
  __bf16* Wb    = (__bf16*)(table + 96 * 512);          // 512*512*2B = 512 KB
  __bf16* xb    = Wb + 512 * 512;                       // 16384*512*2B = 16 MB
  float*  xout  = (float*)(xb + (size_t)N_TOK * 512);   // 16384*512*4B = 32 MB

  setup_kernel<<<352, 256, 0, stream>>>(W, table, Wb);
  wave_kernel<<<N_TOK, 256, 0, stream>>>(char_idx, pos, table, xb);
  dim3 g2(N_TOK / 128, D_DIM / 128);
  mfma_gemm<<<g2, 256, 0, stream>>>(xb, Wb, xout);
  epilogue_kernel<<<N_TOK, 256, 0, stream>>>(xout, char_idx, b, gamma, beta_ln,
                                             noise, sem, (float4*)d_out);
}